// Round 3
// baseline (623.769 us; speedup 1.0000x reference)
//
#include <hip/hip_runtime.h>

// SparseLinear: out[b,k] = dot(embed[b,:], weight[shortlist[b,k],:]) + bias[shortlist[b,k]]
// B=256, K=500, D=512, L=262144 (fp32 everywhere, shortlist delivered as int32)
//
// One 64-lane wave per (b,k) dot: lane i owns d = i*8..i*8+7 (two float4 loads
// = coalesced 2 KB row read). Embed fragment lives in registers across all k's
// the wave handles. Shortlist index for the NEXT k is prefetched before the
// current row's reduction so the idx->row dependency chain is off the critical
// path. Memory-bound: ~262 MB of gathered rows, floor ~42 us at 6.3 TB/s.

#define B_ 256
#define K_ 500
#define D_ 512
#define CHUNK 64   // k's per block (4 waves x 16 k each)
#define NCHUNK 8   // ceil(500/64)

__global__ __launch_bounds__(256, 8)
void sparse_linear_kernel(const float* __restrict__ embed,
                          const int* __restrict__ shortlist,
                          const float* __restrict__ weight,
                          const float* __restrict__ bias,
                          float* __restrict__ out) {
    const int b     = blockIdx.x >> 3;   // NCHUNK = 8 chunks per sample
    const int chunk = blockIdx.x & 7;
    const int tid   = threadIdx.x;
    const int wave  = tid >> 6;
    const int lane  = tid & 63;

    // Embed fragment held in registers: lane covers d = lane*8 .. lane*8+7.
    const float4* e4 = reinterpret_cast<const float4*>(embed + (size_t)b * D_ + lane * 8);
    const float4 e0 = e4[0];
    const float4 e1 = e4[1];

    const int kbeg = chunk * CHUNK + wave;
    const int kend = (chunk * CHUNK + CHUNK < K_) ? chunk * CHUNK + CHUNK : K_;

    int idx = (kbeg < kend) ? shortlist[b * K_ + kbeg] : 0;
    for (int k = kbeg; k < kend; k += 4) {
        // Prefetch next iteration's index: overlaps with this row's gather.
        const int knext = k + 4;
        const int idx_next = (knext < kend) ? shortlist[b * K_ + knext] : 0;

        const float4* w4 =
            reinterpret_cast<const float4*>(weight + (size_t)idx * D_ + lane * 8);
        const float4 w0 = w4[0];   // 64 lanes x 32 B = coalesced 2 KB row read
        const float4 w1 = w4[1];

        float s = e0.x * w0.x + e0.y * w0.y + e0.z * w0.z + e0.w * w0.w
                + e1.x * w1.x + e1.y * w1.y + e1.z * w1.z + e1.w * w1.w;

        // 64-lane butterfly reduction
        #pragma unroll
        for (int off = 32; off > 0; off >>= 1)
            s += __shfl_down(s, off, 64);

        if (lane == 0)
            out[b * K_ + k] = s + bias[idx];

        idx = idx_next;
    }
}

extern "C" void kernel_launch(void* const* d_in, const int* in_sizes, int n_in,
                              void* d_out, int out_size, void* d_ws, size_t ws_size,
                              hipStream_t stream) {
    const float* embed     = (const float*)d_in[0];
    const int*   shortlist = (const int*)  d_in[1];
    const float* weight    = (const float*)d_in[2];
    const float* bias      = (const float*)d_in[3];
    float*       out       = (float*)d_out;

    dim3 grid(B_ * NCHUNK);   // 2048 blocks
    dim3 block(256);          // 4 waves/block -> one (b,k) dot per wave
    sparse_linear_kernel<<<grid, block, 0, stream>>>(embed, shortlist, weight, bias, out);
}

// Round 4
// 621.423 us; speedup vs baseline: 1.0038x; 1.0038x over previous
//
#include <hip/hip_runtime.h>

// SparseLinear: out[b,k] = dot(embed[b,:], weight[shortlist[b,k],:]) + bias[shortlist[b,k]]
// B=256, K=500, D=512, L=262144 (fp32; shortlist delivered as int32)
//
// v2: 4-deep row pipelining. One 64-lane wave per (b,k) dot (lane i owns
// d=i*8..i*8+7, two float4 loads = coalesced 2 KB row). v1 kept only ONE row
// (2 KB) in flight per wave; under loaded-HBM queueing that may starve MLP.
// v2 issues FOUR independent rows (8 KB/wave in flight) before any reduction,
// and interleaves the four 6-step butterfly reductions for shuffle ILP.
// __launch_bounds__(256,4) raises the VGPR cap to 128 so all 8 row fragments
// (32 VGPR) + addresses stay live without spills. Traffic unchanged: ~262 MB
// gathered rows, floor ~42 us at 6.3 TB/s.

#define B_ 256
#define K_ 500
#define D_ 512
#define CHUNK 64   // k's per block (4 waves x 16 k each)
#define NCHUNK 8   // ceil(500/64)

__device__ __forceinline__ float dot8(const float4& e0, const float4& e1,
                                      const float4& w0, const float4& w1) {
    return e0.x * w0.x + e0.y * w0.y + e0.z * w0.z + e0.w * w0.w
         + e1.x * w1.x + e1.y * w1.y + e1.z * w1.z + e1.w * w1.w;
}

__global__ __launch_bounds__(256, 4)
void sparse_linear_kernel(const float* __restrict__ embed,
                          const int* __restrict__ shortlist,
                          const float* __restrict__ weight,
                          const float* __restrict__ bias,
                          float* __restrict__ out) {
    const int b     = blockIdx.x >> 3;   // NCHUNK = 8 chunks per sample
    const int chunk = blockIdx.x & 7;
    const int tid   = threadIdx.x;
    const int wave  = tid >> 6;
    const int lane  = tid & 63;

    // Embed fragment in registers: lane covers d = lane*8 .. lane*8+7.
    const float4* e4 = reinterpret_cast<const float4*>(embed + (size_t)b * D_ + lane * 8);
    const float4 e0 = e4[0];
    const float4 e1 = e4[1];

    const int kbeg = chunk * CHUNK + wave;           // this wave's first k
    const int kend = (chunk * CHUNK + CHUNK < K_) ? chunk * CHUNK + CHUNK : K_;

    for (int k = kbeg; k < kend; k += 16) {          // 4 rows per iteration
        const int k1 = k + 4, k2 = k + 8, k3 = k + 12;
        const bool p1 = k1 < kend, p2 = k2 < kend, p3 = k3 < kend;

        // Wave-uniform index loads (one 4B broadcast each). Out-of-range k's
        // alias row i0: the duplicate load is an L1 hit, store is masked.
        const int i0 = shortlist[b * K_ + k];
        const int i1 = p1 ? shortlist[b * K_ + k1] : i0;
        const int i2 = p2 ? shortlist[b * K_ + k2] : i0;
        const int i3 = p3 ? shortlist[b * K_ + k3] : i0;

        // Issue all 8 row loads (4 rows x 2 float4) before any use:
        // 8 KB in flight per wave, 4 independent HBM row streams.
        const float4* w40 = reinterpret_cast<const float4*>(weight + (size_t)i0 * D_ + lane * 8);
        const float4* w41 = reinterpret_cast<const float4*>(weight + (size_t)i1 * D_ + lane * 8);
        const float4* w42 = reinterpret_cast<const float4*>(weight + (size_t)i2 * D_ + lane * 8);
        const float4* w43 = reinterpret_cast<const float4*>(weight + (size_t)i3 * D_ + lane * 8);
        const float4 a0 = w40[0], c0 = w40[1];
        const float4 a1 = w41[0], c1 = w41[1];
        const float4 a2 = w42[0], c2 = w42[1];
        const float4 a3 = w43[0], c3 = w43[1];

        float s0 = dot8(e0, e1, a0, c0);
        float s1 = dot8(e0, e1, a1, c1);
        float s2 = dot8(e0, e1, a2, c2);
        float s3 = dot8(e0, e1, a3, c3);

        // Four interleaved 64-lane butterfly reductions (shuffle ILP).
        #pragma unroll
        for (int off = 32; off > 0; off >>= 1) {
            s0 += __shfl_xor(s0, off, 64);
            s1 += __shfl_xor(s1, off, 64);
            s2 += __shfl_xor(s2, off, 64);
            s3 += __shfl_xor(s3, off, 64);
        }

        if (lane == 0) {
            out[b * K_ + k] = s0 + bias[i0];
            if (p1) out[b * K_ + k1] = s1 + bias[i1];
            if (p2) out[b * K_ + k2] = s2 + bias[i2];
            if (p3) out[b * K_ + k3] = s3 + bias[i3];
        }
    }
}

extern "C" void kernel_launch(void* const* d_in, const int* in_sizes, int n_in,
                              void* d_out, int out_size, void* d_ws, size_t ws_size,
                              hipStream_t stream) {
    const float* embed     = (const float*)d_in[0];
    const int*   shortlist = (const int*)  d_in[1];
    const float* weight    = (const float*)d_in[2];
    const float* bias      = (const float*)d_in[3];
    float*       out       = (float*)d_out;

    dim3 grid(B_ * NCHUNK);   // 2048 blocks
    dim3 block(256);          // 4 waves/block; 4 rows in flight per wave
    sparse_linear_kernel<<<grid, block, 0, stream>>>(embed, shortlist, weight, bias, out);
}